// Round 13
// baseline (764.209 us; speedup 1.0000x reference)
//
#include <hip/hip_runtime.h>
#include <math.h>

#define EPSQ 1e-5f
#define TOK 8192
#define DM 2048
#define DF 8192
#define NW (DM*DF)
#define NGU 16384   // concatenated gate+up output width

typedef float f32x4 __attribute__((ext_vector_type(4)));
typedef int   int32x4 __attribute__((ext_vector_type(4)));
typedef char  i8x4 __attribute__((ext_vector_type(4)));
typedef char  i8x8 __attribute__((ext_vector_type(8)));
typedef _Float16 f16x8 __attribute__((ext_vector_type(8)));

// ---- fixed workspace layout (bytes) ----
#define OFF_DSUM 0ull                                // 3 doubles
#define OFF_SX   (4ull<<10)                          // 8192 f32
#define OFF_SH   (40ull<<10)                         // 8192 f32
#define OFF_XQ   (1ull<<20)                          // 16MB i8 [8192][2048]
#define OFF_WGQ  (OFF_XQ  + (16ull<<20))             // 16MB i8 [8192][2048]
#define OFF_WUQ  (OFF_WGQ + (16ull<<20))             // 16MB (contiguous after WGQ)
#define OFF_WDQ  (OFF_WUQ + (16ull<<20))             // 16MB i8 [2048][8192]
#define OFF_HQ   (OFF_WDQ + (16ull<<20))             // 64MB i8 [8192][8192]
#define FIXED_END (OFF_HQ + (64ull<<20))             // 129MB
// strip region (after FIXED_END): gu fp16 [S][16384]

#define GLL(gp, lp) __builtin_amdgcn_global_load_lds( \
    (const __attribute__((address_space(1))) unsigned int*)(gp), \
    (__attribute__((address_space(3))) unsigned int*)(lp), 16, 0, 0)

// ---- |w| sums for all three weights (absmean scales), f64 totals ----
__global__ void k_wabs3(const float* __restrict__ w0, const float* __restrict__ w1,
                        const float* __restrict__ w2, double* __restrict__ dsum, int n4) {
  const float* w = blockIdx.y == 0 ? w0 : blockIdx.y == 1 ? w1 : w2;
  const f32x4* w4 = (const f32x4*)w;
  float s = 0.f;
  for (int i = blockIdx.x * blockDim.x + threadIdx.x; i < n4; i += gridDim.x * blockDim.x) {
    f32x4 v = w4[i];
    s += fabsf(v.x) + fabsf(v.y) + fabsf(v.z) + fabsf(v.w);
  }
  __shared__ float red[256];
  red[threadIdx.x] = s; __syncthreads();
  for (int o = 128; o > 0; o >>= 1) {
    if (threadIdx.x < o) red[threadIdx.x] += red[threadIdx.x + o];
    __syncthreads();
  }
  if (threadIdx.x == 0) atomicAdd(dsum + blockIdx.y, (double)red[0]);
}

// ---- ternary-quantize all three weights -> int8 {-1,0,1} (contiguous dest) ----
__global__ void k_quant_w3(const float* __restrict__ w0, const float* __restrict__ w1,
                           const float* __restrict__ w2, char* __restrict__ wqall,
                           const double* __restrict__ dsum, int n4) {
  const float* w = blockIdx.y == 0 ? w0 : blockIdx.y == 1 ? w1 : w2;
  char* wq = wqall + (size_t)blockIdx.y * NW;
  float scale = (float)(dsum[blockIdx.y] / (double)NW) + EPSQ;
  const f32x4* w4 = (const f32x4*)w;
  for (int i = blockIdx.x * blockDim.x + threadIdx.x; i < n4; i += gridDim.x * blockDim.x) {
    f32x4 v = w4[i];
    i8x4 o;
#pragma unroll
    for (int c = 0; c < 4; c++) {
      float q = rintf(v[c] / scale);
      q = fminf(1.f, fmaxf(-1.f, q));
      o[c] = (char)(int)q;
    }
    *(i8x4*)&wq[(size_t)i * 4] = o;
  }
}

// ---- per-token int8 quantize x -> int8 + scale ----
__global__ void k_quant_x(const float* __restrict__ x, char* __restrict__ xq,
                          float* __restrict__ sx) {
  const int row = blockIdx.x;
  const int tid = threadIdx.x;
  const f32x4* xr = (const f32x4*)(x + (size_t)row * DM);
  f32x4 v0 = xr[tid * 2], v1 = xr[tid * 2 + 1];
  float m = 0.f;
#pragma unroll
  for (int c = 0; c < 4; c++) m = fmaxf(m, fmaxf(fabsf(v0[c]), fabsf(v1[c])));
  __shared__ float red[256];
  red[tid] = m; __syncthreads();
  for (int o = 128; o > 0; o >>= 1) {
    if (tid < o) red[tid] = fmaxf(red[tid], red[tid + o]);
    __syncthreads();
  }
  float sc = fmaxf(red[0], EPSQ) / 127.f;
  if (tid == 0) sx[row] = sc;
  i8x8 o;
#pragma unroll
  for (int c = 0; c < 4; c++) {
    float q0 = fminf(127.f, fmaxf(-128.f, rintf(v0[c] / sc)));
    float q1 = fminf(127.f, fmaxf(-128.f, rintf(v1[c] / sc)));
    o[c] = (char)(int)q0; o[c + 4] = (char)(int)q1;
  }
  *(i8x8*)&xq[(size_t)row * DM + tid * 8] = o;
}

// ---- fused h = sigmoid(gate)*up (fp16 gu in), row-max, int8 quantize ----
__global__ void k_gufuse(const _Float16* __restrict__ gu, char* __restrict__ hq,
                         float* __restrict__ sh) {
  const int row = blockIdx.x;
  const int tid = threadIdx.x;
  const f16x8* g8 = (const f16x8*)(gu + (size_t)row * NGU);
  const f16x8* u8 = g8 + (DF / 8);
  float h[32];
  float m = 0.f;
#pragma unroll
  for (int j = 0; j < 4; j++) {
    f16x8 gg = g8[tid * 4 + j];
    f16x8 uu = u8[tid * 4 + j];
#pragma unroll
    for (int c = 0; c < 8; c++) {
      float v = (float)uu[c] / (1.f + expf(-(float)gg[c]));   // sigmoid(g)*u
      h[j * 8 + c] = v;
      m = fmaxf(m, fabsf(v));
    }
  }
  __shared__ float red[256];
  red[tid] = m; __syncthreads();
  for (int o = 128; o > 0; o >>= 1) {
    if (tid < o) red[tid] = fmaxf(red[tid], red[tid + o]);
    __syncthreads();
  }
  float sc = fmaxf(red[0], EPSQ) / 127.f;
  if (tid == 0) sh[row] = sc;
#pragma unroll
  for (int jj = 0; jj < 4; jj++) {
    i8x8 o;
#pragma unroll
    for (int c = 0; c < 8; c++) {
      float q = fminf(127.f, fmaxf(-128.f, rintf(h[jj * 8 + c] / sc)));
      o[c] = (char)(int)q;
    }
    *(i8x8*)&hq[(size_t)row * DF + tid * 32 + jj * 8] = o;
  }
}

// ---- 256x256-tile i8 MFMA GEMM.
//      A: LDS-staged (4-deep ring of 256x64 sub-tiles, 64KB total, T2 swizzle
//         via pre-swizzled GLL source) with register frag double-buffer.
//      B: loaded DIRECTLY global->VGPR (L2/L3-resident weight panels; no
//         swizzle needed; distance-1 reg double-buffer) -- removes 1/3 of
//         the per-iter LDS port time and half the staging GLLs.
//      No setprio (suspected co-wave ds_read starvation). T4 counted vmcnt
//      (6 ops/iter window, fenced by "memory" asm). T1 XCD swizzle.
// C[m,n] = (sum_k A[m,k]*B[n,k]) * rowscale[m] * sw,  sw selected by n0 vs colsplit.
template<typename OT>
__global__ __launch_bounds__(512, 2)
void k_gemm8(const char* __restrict__ A, const char* __restrict__ B,
             OT* __restrict__ C, const float* __restrict__ rowscale,
             const double* __restrict__ dsumA, const double* __restrict__ dsumB,
             int colsplit, int N, int K) {
  __shared__ __align__(16) char smA[4][16384];   // ring of 4 A sub-tiles (256x64 i8)

  const int tid = threadIdx.x;
  const int wv = tid >> 6;          // 0..7
  const int lane = tid & 63;
  const int wm = wv >> 2;           // 0..1  (M half: 128 rows)
  const int wn = wv & 3;            // 0..3  (N quarter: 64 cols)
  const int lr = lane & 15;
  const int g = lane >> 4;          // 0..3  (16B k-slot group)
  const int c3 = (lr >> 1) & 3;     // read-side slot swizzle key

  // bijective XCD swizzle (nwg % 8 == 0 for all our grids)
  const int nwg = gridDim.x * gridDim.y;
  const int bid = blockIdx.y * gridDim.x + blockIdx.x;
  const int lid = (bid & 7) * (nwg >> 3) + (bid >> 3);
  const int gx = N >> 8;
  const int n0 = (lid % gx) << 8;
  const int m0 = (lid / gx) << 8;

  const float sw = (n0 < colsplit)
      ? (float)(*dsumA / (double)NW) + EPSQ
      : (float)(*dsumB / (double)NW) + EPSQ;

  // A staging: one GLL = 1KB = 16 rows x 64B; wave wv stages rows [wv*32,+32):
  // LDS dest linear; source col pre-swizzled: slot = (l&3) ^ ((l>>3)&3).
  const int srow = lane >> 2;                       // 0..15
  const int sslot = (lane & 3) ^ ((lane >> 3) & 3); // pre-swizzled 16B slot
  const char* gA0 = A + (size_t)(m0 + wv * 32 + srow) * K + sslot * 16;
  const char* gA1 = gA0 + (size_t)16 * K;
  const int dst0 = (wv * 32) * 64 + lane * 16;      // byte offset in 16KB plane
  const int dst1 = dst0 + 1024;

  // B direct: lane reads B[n0 + wn*64 + n*16 + lr][s*64 + g*16 .. +16]
  const char* gBr = B + (size_t)(n0 + wn * 64 + lr) * K + g * 16;
  const size_t bstep = (size_t)16 * K;              // +16 rows per n-tile

#define STAGE_A(s) do { \
    const size_t ko_ = (size_t)(s) * 64; \
    char* pA_ = &smA[(s) & 3][0]; \
    GLL(gA0 + ko_, pA_ + dst0); \
    GLL(gA1 + ko_, pA_ + dst1); \
  } while (0)

#define LOADB(BN, s) do { \
    const size_t ko_ = (size_t)(s) * 64; \
    _Pragma("unroll") \
    for (int n = 0; n < 4; n++) \
      BN[n] = *(const int32x4*)(gBr + (size_t)n * bstep + ko_); \
  } while (0)

  int32x4 acc[8][4];
  const int32x4 z4 = {0, 0, 0, 0};
#pragma unroll
  for (int m = 0; m < 8; m++)
#pragma unroll
    for (int n = 0; n < 4; n++) acc[m][n] = z4;

  const int NS = K >> 6;   // sub-tiles of 64 (even, >= 4 for our K)
  const int abase = (wm * 128 + lr) * 64 + ((g ^ c3) << 4);

#define READS_A(NA, slot_) do { \
    const char* smA_ = &smA[(slot_)][0]; \
    _Pragma("unroll") \
    for (int m = 0; m < 8; m++) NA[m] = *(const int32x4*)&smA_[abase + m * 1024]; \
  } while (0)

#define MFMAS(CA, CB) do { \
    _Pragma("unroll") \
    for (int m = 0; m < 8; m++) \
      _Pragma("unroll") \
      for (int n = 0; n < 4; n++) \
        acc[m][n] = __builtin_amdgcn_mfma_i32_16x16x64_i8(CA[m], CB[n], acc[m][n], 0, 0, 0); \
  } while (0)

  int32x4 curA[8], nxtA[8], bCur[4], bNxt[4];

  // prologue: A0(2) B0(4) A1(2) A2(2); wait A0+B0 (newest 4 = A1,A2 remain)
  STAGE_A(0);
  LOADB(bCur, 0);
  STAGE_A(1); STAGE_A(2);
  asm volatile("s_waitcnt vmcnt(4)" ::: "memory");
  __builtin_amdgcn_s_barrier();
  READS_A(curA, 0);

  // per iter (6 vm ops steady): STAGE_A(s+3) + LOADB(s+1) -> vmcnt(6)
  // guarantees A-stage(s) (issued s-3) and B(s) (issued s-1) complete.
#define ITER(sv, CA, NA, BC, BN) do { \
    const int s_ = (sv); \
    if (s_ + 3 < NS) STAGE_A(s_ + 3); \
    if (s_ + 1 < NS) LOADB(BN, s_ + 1); \
    if (s_ + 3 < NS) { \
      asm volatile("s_waitcnt vmcnt(6)" ::: "memory"); \
    } else if (s_ + 1 < NS) { \
      asm volatile("s_waitcnt vmcnt(4)" ::: "memory"); \
    } else { \
      asm volatile("s_waitcnt vmcnt(0)" ::: "memory"); \
    } \
    asm volatile("s_waitcnt lgkmcnt(0)" ::: "memory"); \
    __builtin_amdgcn_sched_barrier(0); \
    __builtin_amdgcn_s_barrier(); \
    if (s_ + 1 < NS) READS_A(NA, (s_ + 1) & 3); \
    MFMAS(CA, BC); \
  } while (0)

  for (int s = 0; s < NS; s += 2) {
    ITER(s, curA, nxtA, bCur, bNxt);
    ITER(s + 1, nxtA, curA, bNxt, bCur);
  }
#undef ITER
#undef READS_A
#undef MFMAS
#undef LOADB
#undef STAGE_A

  // epilogue: C/D layout col = lane&15, row = (lane>>4)*4 + j
#pragma unroll
  for (int m = 0; m < 8; m++) {
#pragma unroll
    for (int j = 0; j < 4; j++) {
      const int row = m0 + wm * 128 + m * 16 + g * 4 + j;
      const float rs = rowscale[row] * sw;
#pragma unroll
      for (int n = 0; n < 4; n++) {
        const int col = n0 + wn * 64 + n * 16 + lr;
        C[(size_t)row * N + col] = (OT)((float)acc[m][n][j] * rs);
      }
    }
  }
}

extern "C" void kernel_launch(void* const* d_in, const int* in_sizes, int n_in,
                              void* d_out, int out_size, void* d_ws, size_t ws_size,
                              hipStream_t stream) {
  const float* x  = (const float*)d_in[0];
  const float* wg = (const float*)d_in[1];
  const float* wu = (const float*)d_in[2];
  const float* wd = (const float*)d_in[3];
  float* out = (float*)d_out;
  char* ws = (char*)d_ws;

  double* dsum = (double*)(ws + OFF_DSUM);
  float* sx = (float*)(ws + OFF_SX);
  float* sh = (float*)(ws + OFF_SH);
  char* xq  = ws + OFF_XQ;
  char* wgq = ws + OFF_WGQ;   // wgq..wuq contiguous = [16384][2048]
  char* wdq = ws + OFF_WDQ;
  char* hq  = ws + OFF_HQ;    // full [8192][8192] int8

  // strip sizing: per row need 16384*2 B (gu fp16); S multiple of 256
  size_t avail = ws_size > FIXED_END ? ws_size - FIXED_END : 0;
  int S = 256;
  for (int cand = 8192; cand >= 256; cand >>= 1) {
    if ((size_t)cand * 32768ull <= avail) { S = cand; break; }
  }
  _Float16* gubuf = (_Float16*)(ws + FIXED_END);

  hipMemsetAsync(ws, 0, 64, stream);

  const int n4 = NW / 4;
  k_wabs3<<<dim3(2048, 3), 256, 0, stream>>>(wg, wu, wd, dsum, n4);
  k_quant_w3<<<dim3(2048, 3), 256, 0, stream>>>(wg, wu, wd, wgq, dsum, n4);
  k_quant_x<<<TOK, 256, 0, stream>>>(x, xq, sx);

  for (int base = 0; base < TOK; base += S) {
    // [gate | up] = xq_strip @ [wgq; wuq]^T  (N = 16384, fp16 out)
    k_gemm8<_Float16><<<dim3(NGU / 256, S / 256), 512, 0, stream>>>(
        xq + (size_t)base * DM, wgq, gubuf, sx + base,
        dsum + 0, dsum + 1, DF, NGU, DM);

    k_gufuse<<<S, 256, 0, stream>>>(gubuf, hq + (size_t)base * DF, sh + base);
  }

  // single down-projection GEMM over all rows (fp32 out)
  k_gemm8<float><<<dim3(DM / 256, TOK / 256), 512, 0, stream>>>(
      hq, wdq, out, sh, dsum + 2, dsum + 2, 1 << 30, DM, DF);
}

// Round 14
// 713.773 us; speedup vs baseline: 1.0707x; 1.0707x over previous
//
#include <hip/hip_runtime.h>
#include <math.h>

#define EPSQ 1e-5f
#define TOK 8192
#define DM 2048
#define DF 8192
#define NW (DM*DF)
#define NGU 16384   // concatenated gate+up output width

typedef float f32x4 __attribute__((ext_vector_type(4)));
typedef int   int32x4 __attribute__((ext_vector_type(4)));
typedef char  i8x4 __attribute__((ext_vector_type(4)));
typedef char  i8x8 __attribute__((ext_vector_type(8)));
typedef _Float16 f16x8 __attribute__((ext_vector_type(8)));

// ---- fixed workspace layout (bytes) ----
#define OFF_DSUM 0ull                                // 3 doubles
#define OFF_SX   (4ull<<10)                          // 8192 f32
#define OFF_SH   (40ull<<10)                         // 8192 f32
#define OFF_XQ   (1ull<<20)                          // 16MB i8 [8192][2048]
#define OFF_WGQ  (OFF_XQ  + (16ull<<20))             // 16MB i8 [8192][2048]
#define OFF_WUQ  (OFF_WGQ + (16ull<<20))             // 16MB (contiguous after WGQ)
#define OFF_WDQ  (OFF_WUQ + (16ull<<20))             // 16MB i8 [2048][8192]
#define OFF_HQ   (OFF_WDQ + (16ull<<20))             // 64MB i8 [8192][8192]
#define FIXED_END (OFF_HQ + (64ull<<20))             // 129MB
// strip region (after FIXED_END): gu fp16 [S][16384]

#define GLL(gp, lp) __builtin_amdgcn_global_load_lds( \
    (const __attribute__((address_space(1))) unsigned int*)(gp), \
    (__attribute__((address_space(3))) unsigned int*)(lp), 16, 0, 0)

// ---- |w| sums for all three weights (absmean scales), f64 totals ----
__global__ void k_wabs3(const float* __restrict__ w0, const float* __restrict__ w1,
                        const float* __restrict__ w2, double* __restrict__ dsum, int n4) {
  const float* w = blockIdx.y == 0 ? w0 : blockIdx.y == 1 ? w1 : w2;
  const f32x4* w4 = (const f32x4*)w;
  float s = 0.f;
  for (int i = blockIdx.x * blockDim.x + threadIdx.x; i < n4; i += gridDim.x * blockDim.x) {
    f32x4 v = w4[i];
    s += fabsf(v.x) + fabsf(v.y) + fabsf(v.z) + fabsf(v.w);
  }
  __shared__ float red[256];
  red[threadIdx.x] = s; __syncthreads();
  for (int o = 128; o > 0; o >>= 1) {
    if (threadIdx.x < o) red[threadIdx.x] += red[threadIdx.x + o];
    __syncthreads();
  }
  if (threadIdx.x == 0) atomicAdd(dsum + blockIdx.y, (double)red[0]);
}

// ---- ternary-quantize all three weights -> int8 {-1,0,1} (contiguous dest) ----
__global__ void k_quant_w3(const float* __restrict__ w0, const float* __restrict__ w1,
                           const float* __restrict__ w2, char* __restrict__ wqall,
                           const double* __restrict__ dsum, int n4) {
  const float* w = blockIdx.y == 0 ? w0 : blockIdx.y == 1 ? w1 : w2;
  char* wq = wqall + (size_t)blockIdx.y * NW;
  float scale = (float)(dsum[blockIdx.y] / (double)NW) + EPSQ;
  const f32x4* w4 = (const f32x4*)w;
  for (int i = blockIdx.x * blockDim.x + threadIdx.x; i < n4; i += gridDim.x * blockDim.x) {
    f32x4 v = w4[i];
    i8x4 o;
#pragma unroll
    for (int c = 0; c < 4; c++) {
      float q = rintf(v[c] / scale);
      q = fminf(1.f, fmaxf(-1.f, q));
      o[c] = (char)(int)q;
    }
    *(i8x4*)&wq[(size_t)i * 4] = o;
  }
}

// ---- per-token int8 quantize x -> int8 + scale ----
__global__ void k_quant_x(const float* __restrict__ x, char* __restrict__ xq,
                          float* __restrict__ sx) {
  const int row = blockIdx.x;
  const int tid = threadIdx.x;
  const f32x4* xr = (const f32x4*)(x + (size_t)row * DM);
  f32x4 v0 = xr[tid * 2], v1 = xr[tid * 2 + 1];
  float m = 0.f;
#pragma unroll
  for (int c = 0; c < 4; c++) m = fmaxf(m, fmaxf(fabsf(v0[c]), fabsf(v1[c])));
  __shared__ float red[256];
  red[tid] = m; __syncthreads();
  for (int o = 128; o > 0; o >>= 1) {
    if (tid < o) red[tid] = fmaxf(red[tid], red[tid + o]);
    __syncthreads();
  }
  float sc = fmaxf(red[0], EPSQ) / 127.f;
  if (tid == 0) sx[row] = sc;
  i8x8 o;
#pragma unroll
  for (int c = 0; c < 4; c++) {
    float q0 = fminf(127.f, fmaxf(-128.f, rintf(v0[c] / sc)));
    float q1 = fminf(127.f, fmaxf(-128.f, rintf(v1[c] / sc)));
    o[c] = (char)(int)q0; o[c + 4] = (char)(int)q1;
  }
  *(i8x8*)&xq[(size_t)row * DM + tid * 8] = o;
}

// ---- fused h = sigmoid(gate)*up (fp16 gu in), row-max, int8 quantize ----
__global__ void k_gufuse(const _Float16* __restrict__ gu, char* __restrict__ hq,
                         float* __restrict__ sh) {
  const int row = blockIdx.x;
  const int tid = threadIdx.x;
  const f16x8* g8 = (const f16x8*)(gu + (size_t)row * NGU);
  const f16x8* u8 = g8 + (DF / 8);
  float h[32];
  float m = 0.f;
#pragma unroll
  for (int j = 0; j < 4; j++) {
    f16x8 gg = g8[tid * 4 + j];
    f16x8 uu = u8[tid * 4 + j];
#pragma unroll
    for (int c = 0; c < 8; c++) {
      float v = (float)uu[c] / (1.f + expf(-(float)gg[c]));   // sigmoid(g)*u
      h[j * 8 + c] = v;
      m = fmaxf(m, fabsf(v));
    }
  }
  __shared__ float red[256];
  red[tid] = m; __syncthreads();
  for (int o = 128; o > 0; o >>= 1) {
    if (tid < o) red[tid] = fmaxf(red[tid], red[tid + o]);
    __syncthreads();
  }
  float sc = fmaxf(red[0], EPSQ) / 127.f;
  if (tid == 0) sh[row] = sc;
#pragma unroll
  for (int jj = 0; jj < 4; jj++) {
    i8x8 o;
#pragma unroll
    for (int c = 0; c < 8; c++) {
      float q = fminf(127.f, fmaxf(-128.f, rintf(h[jj * 8 + c] / sc)));
      o[c] = (char)(int)q;
    }
    *(i8x8*)&hq[(size_t)row * DF + tid * 32 + jj * 8] = o;
  }
}

// ---- 256x256-tile i8 MFMA GEMM, 4 WAVES, per-wave 128x128 output tile:
//      16 ds_read_b128 feed 64 MFMAs per sub-tile (0.25 reads/MFMA vs 0.375)
//      -> LDS port time per iter 768 cyc vs MFMA 1306 cyc. 1 wave/SIMD
//      (launch_bounds(256,1), acc 8x8 = 256 VGPR) relies on ILP: 64
//      independent MFMAs saturate the pipe, reads/stages issue between them.
//      4-deep LDS ring of BK=64 slots (A 16KB + B 16KB = 32KB/slot, 128KB),
//      frag double-buffer, barrier/iter, counted vmcnt (16/8/0 ladder),
//      T2 swizzle via pre-swizzled GLL source, T1 XCD swizzle.
// C[m,n] = (sum_k A[m,k]*B[n,k]) * rowscale[m] * sw,  sw selected by n0 vs colsplit.
template<typename OT>
__global__ __launch_bounds__(256, 1)
void k_gemm4(const char* __restrict__ A, const char* __restrict__ B,
             OT* __restrict__ C, const float* __restrict__ rowscale,
             const double* __restrict__ dsumA, const double* __restrict__ dsumB,
             int colsplit, int N, int K) {
  __shared__ __align__(16) char sm[4][32768];   // slot: A @0 (16KB), B @16384 (16KB)

  const int tid = threadIdx.x;
  const int wv = tid >> 6;          // 0..3
  const int lane = tid & 63;
  const int wm = wv >> 1;           // 0..1  (M half: 128 rows)
  const int wn = wv & 1;            // 0..1  (N half: 128 cols)
  const int lr = lane & 15;
  const int g = lane >> 4;          // 0..3  (16B k-slot group)
  const int c3 = (lr >> 1) & 3;     // read-side slot swizzle key

  // bijective XCD swizzle (nwg % 8 == 0 for all our grids)
  const int nwg = gridDim.x * gridDim.y;
  const int bid = blockIdx.y * gridDim.x + blockIdx.x;
  const int lid = (bid & 7) * (nwg >> 3) + (bid >> 3);
  const int gx = N >> 8;
  const int n0 = (lid % gx) << 8;
  const int m0 = (lid / gx) << 8;

  const float sw = (n0 < colsplit)
      ? (float)(*dsumA / (double)NW) + EPSQ
      : (float)(*dsumB / (double)NW) + EPSQ;

  // staging: one GLL = 1KB = 16 rows x 64B. wave wv stages rows [wv*64,+64)
  // of A and of B: 4 chunks each (8 GLL/wave/sub-tile).
  // LDS dest linear; source col pre-swizzled: slot = (l&3) ^ ((l>>3)&3).
  const int srow = lane >> 2;                       // 0..15
  const int sslot = (lane & 3) ^ ((lane >> 3) & 3); // pre-swizzled 16B slot
  const char* gA0 = A + (size_t)(m0 + wv * 64 + srow) * K + sslot * 16;
  const char* gB0 = B + (size_t)(n0 + wv * 64 + srow) * K + sslot * 16;
  const size_t cstep = (size_t)16 * K;              // +16 rows per chunk
  const int dstA = wv * 4096 + lane * 16;           // byte offset, A plane
  const int dstB = 16384 + wv * 4096 + lane * 16;   // byte offset, B plane

#define STAGE(s) do { \
    const size_t ko_ = (size_t)(s) * 64; \
    char* p_ = &sm[(s) & 3][0]; \
    _Pragma("unroll") \
    for (int c = 0; c < 4; c++) { \
      GLL(gA0 + (size_t)c * cstep + ko_, p_ + dstA + c * 1024); \
      GLL(gB0 + (size_t)c * cstep + ko_, p_ + dstB + c * 1024); \
    } \
  } while (0)

  int32x4 acc[8][8];
  const int32x4 z4 = {0, 0, 0, 0};
#pragma unroll
  for (int m = 0; m < 8; m++)
#pragma unroll
    for (int n = 0; n < 8; n++) acc[m][n] = z4;

  const int NS = K >> 6;   // sub-tiles of 64 (even, >= 4 for our K)
  const int abase = (wm * 128 + lr) * 64 + ((g ^ c3) << 4);
  const int bbase = 16384 + (wn * 128 + lr) * 64 + ((g ^ c3) << 4);

#define READS(NA, NB, slot_) do { \
    const char* p_ = &sm[(slot_)][0]; \
    _Pragma("unroll") \
    for (int m = 0; m < 8; m++) NA[m] = *(const int32x4*)&p_[abase + m * 1024]; \
    _Pragma("unroll") \
    for (int n = 0; n < 8; n++) NB[n] = *(const int32x4*)&p_[bbase + n * 1024]; \
  } while (0)

#define MFMAS(CA, CB) do { \
    _Pragma("unroll") \
    for (int m = 0; m < 8; m++) \
      _Pragma("unroll") \
      for (int n = 0; n < 8; n++) \
        acc[m][n] = __builtin_amdgcn_mfma_i32_16x16x64_i8(CA[m], CB[n], acc[m][n], 0, 0, 0); \
  } while (0)

  int32x4 curA[8], curB[8], nxtA[8], nxtB[8];

  // prologue: stage 0,1,2 (24 GLL); vmcnt(16) -> slot 0 landed; read cur frags
  STAGE(0); STAGE(1); STAGE(2);
  asm volatile("s_waitcnt vmcnt(16)" ::: "memory");
  __builtin_amdgcn_s_barrier();
  READS(curA, curB, 0);

  // per iter: STAGE(s+3) (8 GLL) -> vmcnt(16) leaves stages s+2,s+3 in
  // flight, certifies s+1 (READS target). lgkm(0) drains prior reads before
  // the barrier that precedes slot (s+3)&3's overwrite (hazard-audited).
#define ITER(sv, CA, CB, NA, NB) do { \
    const int s_ = (sv); \
    if (s_ + 3 < NS) { \
      STAGE(s_ + 3); \
      asm volatile("s_waitcnt vmcnt(16)" ::: "memory"); \
    } else if (s_ + 2 < NS) { \
      asm volatile("s_waitcnt vmcnt(8)" ::: "memory"); \
    } else if (s_ + 1 < NS) { \
      asm volatile("s_waitcnt vmcnt(0)" ::: "memory"); \
    } \
    asm volatile("s_waitcnt lgkmcnt(0)" ::: "memory"); \
    __builtin_amdgcn_sched_barrier(0); \
    __builtin_amdgcn_s_barrier(); \
    if (s_ + 1 < NS) READS(NA, NB, (s_ + 1) & 3); \
    MFMAS(CA, CB); \
  } while (0)

  for (int s = 0; s < NS; s += 2) {
    ITER(s, curA, curB, nxtA, nxtB);
    ITER(s + 1, nxtA, nxtB, curA, curB);
  }
#undef ITER
#undef READS
#undef MFMAS
#undef STAGE

  // epilogue: C/D layout col = lane&15, row = (lane>>4)*4 + j
#pragma unroll
  for (int m = 0; m < 8; m++) {
#pragma unroll
    for (int j = 0; j < 4; j++) {
      const int row = m0 + wm * 128 + m * 16 + g * 4 + j;
      const float rs = rowscale[row] * sw;
#pragma unroll
      for (int n = 0; n < 8; n++) {
        const int col = n0 + wn * 128 + n * 16 + lr;
        C[(size_t)row * N + col] = (OT)((float)acc[m][n][j] * rs);
      }
    }
  }
}

extern "C" void kernel_launch(void* const* d_in, const int* in_sizes, int n_in,
                              void* d_out, int out_size, void* d_ws, size_t ws_size,
                              hipStream_t stream) {
  const float* x  = (const float*)d_in[0];
  const float* wg = (const float*)d_in[1];
  const float* wu = (const float*)d_in[2];
  const float* wd = (const float*)d_in[3];
  float* out = (float*)d_out;
  char* ws = (char*)d_ws;

  double* dsum = (double*)(ws + OFF_DSUM);
  float* sx = (float*)(ws + OFF_SX);
  float* sh = (float*)(ws + OFF_SH);
  char* xq  = ws + OFF_XQ;
  char* wgq = ws + OFF_WGQ;   // wgq..wuq contiguous = [16384][2048]
  char* wdq = ws + OFF_WDQ;
  char* hq  = ws + OFF_HQ;    // full [8192][8192] int8

  // strip sizing: per row need 16384*2 B (gu fp16); S multiple of 256
  size_t avail = ws_size > FIXED_END ? ws_size - FIXED_END : 0;
  int S = 256;
  for (int cand = 8192; cand >= 256; cand >>= 1) {
    if ((size_t)cand * 32768ull <= avail) { S = cand; break; }
  }
  _Float16* gubuf = (_Float16*)(ws + FIXED_END);

  hipMemsetAsync(ws, 0, 64, stream);

  const int n4 = NW / 4;
  k_wabs3<<<dim3(2048, 3), 256, 0, stream>>>(wg, wu, wd, dsum, n4);
  k_quant_w3<<<dim3(2048, 3), 256, 0, stream>>>(wg, wu, wd, wgq, dsum, n4);
  k_quant_x<<<TOK, 256, 0, stream>>>(x, xq, sx);

  for (int base = 0; base < TOK; base += S) {
    // [gate | up] = xq_strip @ [wgq; wuq]^T  (N = 16384, fp16 out)
    k_gemm4<_Float16><<<dim3(NGU / 256, S / 256), 256, 0, stream>>>(
        xq + (size_t)base * DM, wgq, gubuf, sx + base,
        dsum + 0, dsum + 1, DF, NGU, DM);

    k_gufuse<<<S, 256, 0, stream>>>(gubuf, hq + (size_t)base * DF, sh + base);
  }

  // single down-projection GEMM over all rows (fp32 out)
  k_gemm4<float><<<dim3(DM / 256, TOK / 256), 256, 0, stream>>>(
      hq, wdq, out, sh, dsum + 2, dsum + 2, 1 << 30, DM, DF);
}

// Round 15
// 626.188 us; speedup vs baseline: 1.2204x; 1.1399x over previous
//
#include <hip/hip_runtime.h>
#include <math.h>

#define EPSQ 1e-5f
#define TOK 8192
#define DM 2048
#define DF 8192
#define NW (DM*DF)
#define NGU 16384   // interleaved gate/up weight rows (16-row groups)

typedef float f32x4 __attribute__((ext_vector_type(4)));
typedef int   int32x4 __attribute__((ext_vector_type(4)));
typedef char  i8x4 __attribute__((ext_vector_type(4)));
typedef char  i8x8 __attribute__((ext_vector_type(8)));
typedef _Float16 f16x8 __attribute__((ext_vector_type(8)));

// ---- fixed workspace layout (bytes) ----
#define OFF_DSUM 0ull                                // 3 doubles
#define OFF_SX   (4ull<<10)                          // 8192 f32
#define OFF_SH   (40ull<<10)                         // 8192 f32
#define OFF_XQ   (1ull<<20)                          // 16MB i8 [8192][2048]
#define OFF_WCAT (OFF_XQ  + (16ull<<20))             // 32MB i8 [16384][2048] gate/up interleaved
#define OFF_WDQ  (OFF_WCAT + (32ull<<20))            // 16MB i8 [2048][8192]
#define OFF_HQ   (OFF_WDQ + (16ull<<20))             // 64MB i8 [8192][8192]
#define FIXED_END (OFF_HQ + (64ull<<20))             // 129MB
// strip region (after FIXED_END): h fp16 [S][8192]

#define GLL(gp, lp) __builtin_amdgcn_global_load_lds( \
    (const __attribute__((address_space(1))) unsigned int*)(gp), \
    (__attribute__((address_space(3))) unsigned int*)(lp), 16, 0, 0)

// ---- |w| sums for all three weights (absmean scales), f64 totals ----
__global__ void k_wabs3(const float* __restrict__ w0, const float* __restrict__ w1,
                        const float* __restrict__ w2, double* __restrict__ dsum, int n4) {
  const float* w = blockIdx.y == 0 ? w0 : blockIdx.y == 1 ? w1 : w2;
  const f32x4* w4 = (const f32x4*)w;
  float s = 0.f;
  for (int i = blockIdx.x * blockDim.x + threadIdx.x; i < n4; i += gridDim.x * blockDim.x) {
    f32x4 v = w4[i];
    s += fabsf(v.x) + fabsf(v.y) + fabsf(v.z) + fabsf(v.w);
  }
  __shared__ float red[256];
  red[threadIdx.x] = s; __syncthreads();
  for (int o = 128; o > 0; o >>= 1) {
    if (threadIdx.x < o) red[threadIdx.x] += red[threadIdx.x + o];
    __syncthreads();
  }
  if (threadIdx.x == 0) atomicAdd(dsum + blockIdx.y, (double)red[0]);
}

// ---- ternary-quantize weights -> int8 {-1,0,1}.
// gate/up (y=0/1) write INTERLEAVED 16-row groups into wq_gu:
//   src row r -> R = 32*(r/16) + 16*y + (r%16); down (y=2) writes plain wq_d.
__global__ void k_quant_w3(const float* __restrict__ w0, const float* __restrict__ w1,
                           const float* __restrict__ w2, char* __restrict__ wq_gu,
                           char* __restrict__ wq_d, const double* __restrict__ dsum, int n4) {
  const int y = blockIdx.y;
  const float* w = y == 0 ? w0 : y == 1 ? w1 : w2;
  float scale = (float)(dsum[y] / (double)NW) + EPSQ;
  const f32x4* w4 = (const f32x4*)w;
  for (int i = blockIdx.x * blockDim.x + threadIdx.x; i < n4; i += gridDim.x * blockDim.x) {
    f32x4 v = w4[i];
    i8x4 o;
#pragma unroll
    for (int c = 0; c < 4; c++) {
      float q = rintf(v[c] / scale);
      q = fminf(1.f, fmaxf(-1.f, q));
      o[c] = (char)(int)q;
    }
    if (y < 2) {
      const int r = i >> 9, c4 = i & 511;        // 512 x f32x4 chunks per 2048-row
      const int R = ((r & ~15) << 1) + (y << 4) + (r & 15);
      *(i8x4*)&wq_gu[((size_t)R * 512 + c4) * 4] = o;
    } else {
      *(i8x4*)&wq_d[(size_t)i * 4] = o;
    }
  }
}

// ---- per-token int8 quantize x -> int8 + scale ----
__global__ void k_quant_x(const float* __restrict__ x, char* __restrict__ xq,
                          float* __restrict__ sx) {
  const int row = blockIdx.x;
  const int tid = threadIdx.x;
  const f32x4* xr = (const f32x4*)(x + (size_t)row * DM);
  f32x4 v0 = xr[tid * 2], v1 = xr[tid * 2 + 1];
  float m = 0.f;
#pragma unroll
  for (int c = 0; c < 4; c++) m = fmaxf(m, fmaxf(fabsf(v0[c]), fabsf(v1[c])));
  __shared__ float red[256];
  red[tid] = m; __syncthreads();
  for (int o = 128; o > 0; o >>= 1) {
    if (tid < o) red[tid] = fmaxf(red[tid], red[tid + o]);
    __syncthreads();
  }
  float sc = fmaxf(red[0], EPSQ) / 127.f;
  if (tid == 0) sx[row] = sc;
  i8x8 o;
#pragma unroll
  for (int c = 0; c < 4; c++) {
    float q0 = fminf(127.f, fmaxf(-128.f, rintf(v0[c] / sc)));
    float q1 = fminf(127.f, fmaxf(-128.f, rintf(v1[c] / sc)));
    o[c] = (char)(int)q0; o[c + 4] = (char)(int)q1;
  }
  *(i8x8*)&xq[(size_t)row * DM + tid * 8] = o;
}

// ---- row max + int8 quantize of h (fp16) ----
__global__ void k_hquant(const _Float16* __restrict__ h, char* __restrict__ hq,
                         float* __restrict__ sh) {
  const int row = blockIdx.x;
  const int tid = threadIdx.x;
  const f16x8* h8 = (const f16x8*)(h + (size_t)row * DF);
  float hv[32];
  float m = 0.f;
#pragma unroll
  for (int j = 0; j < 4; j++) {
    f16x8 v = h8[tid * 4 + j];
#pragma unroll
    for (int c = 0; c < 8; c++) {
      float f = (float)v[c];
      hv[j * 8 + c] = f;
      m = fmaxf(m, fabsf(f));
    }
  }
  __shared__ float red[256];
  red[tid] = m; __syncthreads();
  for (int o = 128; o > 0; o >>= 1) {
    if (tid < o) red[tid] = fmaxf(red[tid], red[tid + o]);
    __syncthreads();
  }
  float sc = fmaxf(red[0], EPSQ) / 127.f;
  if (tid == 0) sh[row] = sc;
#pragma unroll
  for (int jj = 0; jj < 4; jj++) {
    i8x8 o;
#pragma unroll
    for (int c = 0; c < 8; c++) {
      float q = fminf(127.f, fmaxf(-128.f, rintf(hv[jj * 8 + c] / sc)));
      o[c] = (char)(int)q;
    }
    *(i8x8*)&hq[(size_t)row * DF + tid * 32 + jj * 8] = o;
  }
}

// ---- 256x256-tile i8 MFMA GEMM (r10 structure: 4-deep BK=64 ring, frag
//      double-buffer, counted vmcnt 8/4/0, T2 swizzle via pre-swizzled GLL
//      source, setprio+sched_group interleave, T1 XCD swizzle).
// FUSE=0: C[row*N+col] = acc * rowscale[row] * swA           (OT = float)
// FUSE=1: weight cols are gate/up interleaved (16-col groups); epilogue
//         computes h = sigmoid(g)*u per pair and writes fp16 h at
//         h[row*(N/2) + (n0+wn*64)/2 + p*16 + lr]            (OT = _Float16)
template<int FUSE, typename OT>
__global__ __launch_bounds__(512, 2)
void k_gemm8(const char* __restrict__ A, const char* __restrict__ B,
             OT* __restrict__ C, const float* __restrict__ rowscale,
             const double* __restrict__ dsumA, const double* __restrict__ dsumB,
             int N, int K) {
  __shared__ __align__(16) char sm[4][2][16384];

  const int tid = threadIdx.x;
  const int wv = tid >> 6;
  const int lane = tid & 63;
  const int wm = wv >> 2;
  const int wn = wv & 3;
  const int lr = lane & 15;
  const int g = lane >> 4;
  const int c3 = (lr >> 1) & 3;

  const int nwg = gridDim.x * gridDim.y;
  const int bid = blockIdx.y * gridDim.x + blockIdx.x;
  const int lid = (bid & 7) * (nwg >> 3) + (bid >> 3);
  const int gx = N >> 8;
  const int n0 = (lid % gx) << 8;
  const int m0 = (lid / gx) << 8;

  const float swA = (float)(*dsumA / (double)NW) + EPSQ;
  const float swB = (float)(*dsumB / (double)NW) + EPSQ;

  const int srow = lane >> 2;
  const int sslot = (lane & 3) ^ ((lane >> 3) & 3);
  const char* gA0 = A + (size_t)(m0 + wv * 32 + srow) * K + sslot * 16;
  const char* gA1 = gA0 + (size_t)16 * K;
  const char* gB0 = B + (size_t)(n0 + wv * 32 + srow) * K + sslot * 16;
  const char* gB1 = gB0 + (size_t)16 * K;
  const int dst0 = (wv * 32) * 64 + lane * 16;
  const int dst1 = dst0 + 1024;

#define STAGE(s) do { \
    const size_t ko_ = (size_t)(s) * 64; \
    char* pA_ = &sm[(s) & 3][0][0]; \
    char* pB_ = &sm[(s) & 3][1][0]; \
    GLL(gA0 + ko_, pA_ + dst0); \
    GLL(gA1 + ko_, pA_ + dst1); \
    GLL(gB0 + ko_, pB_ + dst0); \
    GLL(gB1 + ko_, pB_ + dst1); \
  } while (0)

  int32x4 acc[8][4];
  const int32x4 z4 = {0, 0, 0, 0};
#pragma unroll
  for (int m = 0; m < 8; m++)
#pragma unroll
    for (int n = 0; n < 4; n++) acc[m][n] = z4;

  const int NS = K >> 6;
  const int abase = (wm * 128 + lr) * 64 + ((g ^ c3) << 4);
  const int bbase = (wn * 64 + lr) * 64 + ((g ^ c3) << 4);

#define READS(NA, NB, slot_) do { \
    const char* smA_ = &sm[(slot_)][0][0]; \
    const char* smB_ = &sm[(slot_)][1][0]; \
    _Pragma("unroll") \
    for (int n = 0; n < 4; n++) NB[n] = *(const int32x4*)&smB_[bbase + n * 1024]; \
    _Pragma("unroll") \
    for (int m = 0; m < 8; m++) NA[m] = *(const int32x4*)&smA_[abase + m * 1024]; \
  } while (0)

#define MFMAS(CA, CB) do { \
    _Pragma("unroll") \
    for (int m = 0; m < 8; m++) \
      _Pragma("unroll") \
      for (int n = 0; n < 4; n++) \
        acc[m][n] = __builtin_amdgcn_mfma_i32_16x16x64_i8(CA[m], CB[n], acc[m][n], 0, 0, 0); \
  } while (0)

#define INTERLEAVE() do { \
    _Pragma("unroll") \
    for (int gg = 0; gg < 6; gg++) { \
      __builtin_amdgcn_sched_group_barrier(0x100, 2, 0); \
      __builtin_amdgcn_sched_group_barrier(0x008, 5, 0); \
    } \
    __builtin_amdgcn_sched_group_barrier(0x008, 2, 0); \
  } while (0)

#define ITER(sv, CA, CB, NA, NB) do { \
    const int s_ = (sv); \
    const int ahead_ = NS - 1 - s_; \
    if (ahead_ >= 3) { \
      STAGE(s_ + 3); \
      asm volatile("s_waitcnt vmcnt(8)" ::: "memory"); \
    } else if (ahead_ == 2) { \
      asm volatile("s_waitcnt vmcnt(4)" ::: "memory"); \
    } else { \
      asm volatile("s_waitcnt vmcnt(0)" ::: "memory"); \
    } \
    asm volatile("s_waitcnt lgkmcnt(0)" ::: "memory"); \
    __builtin_amdgcn_sched_barrier(0); \
    __builtin_amdgcn_s_barrier(); \
    __builtin_amdgcn_s_setprio(1); \
    READS(NA, NB, (s_ + 1) & 3); \
    MFMAS(CA, CB); \
    INTERLEAVE(); \
    __builtin_amdgcn_s_setprio(0); \
  } while (0)

  STAGE(0); STAGE(1); STAGE(2);
  asm volatile("s_waitcnt vmcnt(8)" ::: "memory");
  __builtin_amdgcn_s_barrier();

  int32x4 curA[8], curB[4], nxtA[8], nxtB[4];
  READS(curA, curB, 0);

  for (int s = 0; s + 1 < NS - 1; s += 2) {
    ITER(s, curA, curB, nxtA, nxtB);
    ITER(s + 1, nxtA, nxtB, curA, curB);
  }
  ITER(NS - 2, curA, curB, nxtA, nxtB);

  asm volatile("s_waitcnt lgkmcnt(0)" ::: "memory");
  __builtin_amdgcn_sched_barrier(0);
  __builtin_amdgcn_s_setprio(1);
  MFMAS(nxtA, nxtB);
  __builtin_amdgcn_s_setprio(0);
#undef ITER
#undef INTERLEAVE
#undef READS
#undef MFMAS
#undef STAGE

  // epilogue: C/D layout col = lane&15, row = (lane>>4)*4 + j
  if constexpr (FUSE) {
    const int hbase = (n0 + wn * 64) >> 1;
#pragma unroll
    for (int m = 0; m < 8; m++) {
#pragma unroll
      for (int j = 0; j < 4; j++) {
        const int row = m0 + wm * 128 + m * 16 + g * 4 + j;
        const float rs = rowscale[row];
#pragma unroll
        for (int p = 0; p < 2; p++) {
          const float gv = (float)acc[m][2 * p][j] * rs * swA;
          const float uv = (float)acc[m][2 * p + 1][j] * rs * swB;
          const float hv = uv / (1.f + expf(-gv));
          C[(size_t)row * (N >> 1) + hbase + p * 16 + lr] = (OT)hv;
        }
      }
    }
  } else {
#pragma unroll
    for (int m = 0; m < 8; m++) {
#pragma unroll
      for (int j = 0; j < 4; j++) {
        const int row = m0 + wm * 128 + m * 16 + g * 4 + j;
        const float rs = rowscale[row] * swA;
#pragma unroll
        for (int n = 0; n < 4; n++) {
          const int col = n0 + wn * 64 + n * 16 + lr;
          C[(size_t)row * N + col] = (OT)((float)acc[m][n][j] * rs);
        }
      }
    }
  }
}

extern "C" void kernel_launch(void* const* d_in, const int* in_sizes, int n_in,
                              void* d_out, int out_size, void* d_ws, size_t ws_size,
                              hipStream_t stream) {
  const float* x  = (const float*)d_in[0];
  const float* wg = (const float*)d_in[1];
  const float* wu = (const float*)d_in[2];
  const float* wd = (const float*)d_in[3];
  float* out = (float*)d_out;
  char* ws = (char*)d_ws;

  double* dsum = (double*)(ws + OFF_DSUM);
  float* sx = (float*)(ws + OFF_SX);
  float* sh = (float*)(ws + OFF_SH);
  char* xq   = ws + OFF_XQ;
  char* wcat = ws + OFF_WCAT;  // [16384][2048] gate/up interleaved (16-row groups)
  char* wdq  = ws + OFF_WDQ;
  char* hq   = ws + OFF_HQ;    // full [8192][8192] int8

  // strip sizing: per row need 8192*2 B (h fp16); S multiple of 256
  size_t avail = ws_size > FIXED_END ? ws_size - FIXED_END : 0;
  int S = 256;
  for (int cand = 8192; cand >= 256; cand >>= 1) {
    if ((size_t)cand * 16384ull <= avail) { S = cand; break; }
  }
  _Float16* hbuf = (_Float16*)(ws + FIXED_END);

  hipMemsetAsync(ws, 0, 64, stream);

  const int n4 = NW / 4;
  k_wabs3<<<dim3(2048, 3), 256, 0, stream>>>(wg, wu, wd, dsum, n4);
  k_quant_w3<<<dim3(2048, 3), 256, 0, stream>>>(wg, wu, wd, wcat, wdq, dsum, n4);
  k_quant_x<<<TOK, 256, 0, stream>>>(x, xq, sx);

  for (int base = 0; base < TOK; base += S) {
    // h = sigmoid(x@wg^T) * (x@wu^T) computed in one GEMM over interleaved
    // w_cat (N = 16384 weight cols -> 8192 fp16 h cols per row)
    k_gemm8<1, _Float16><<<dim3(NGU / 256, S / 256), 512, 0, stream>>>(
        xq + (size_t)base * DM, wcat, hbuf, sx + base,
        dsum + 0, dsum + 1, NGU, DM);

    k_hquant<<<S, 256, 0, stream>>>(hbuf, hq + (size_t)base * DF, sh + base);
  }

  // single down-projection GEMM over all rows (fp32 out)
  k_gemm8<0, float><<<dim3(DM / 256, TOK / 256), 512, 0, stream>>>(
      hq, wdq, out, sh, dsum + 2, dsum + 2, DM, DF);
}

// Round 16
// 621.938 us; speedup vs baseline: 1.2288x; 1.0068x over previous
//
#include <hip/hip_runtime.h>
#include <math.h>

#define EPSQ 1e-5f
#define TOK 8192
#define DM 2048
#define DF 8192
#define NW (DM*DF)
#define NGU 16384   // interleaved gate/up weight rows (16-row groups)

typedef float f32x4 __attribute__((ext_vector_type(4)));
typedef int   int32x4 __attribute__((ext_vector_type(4)));
typedef char  i8x4 __attribute__((ext_vector_type(4)));
typedef char  i8x8 __attribute__((ext_vector_type(8)));
typedef _Float16 f16x8 __attribute__((ext_vector_type(8)));

// ---- fixed workspace layout (bytes) ----
#define OFF_DSUM 0ull                                // 3 doubles
#define OFF_SX   (4ull<<10)                          // 8192 f32
#define OFF_SH   (40ull<<10)                         // 8192 f32
#define OFF_XQ   (1ull<<20)                          // 16MB i8 [8192][2048]
#define OFF_WCAT (OFF_XQ  + (16ull<<20))             // 32MB i8 [16384][2048] gate/up interleaved
#define OFF_WDQ  (OFF_WCAT + (32ull<<20))            // 16MB i8 [2048][8192]
#define OFF_HQ   (OFF_WDQ + (16ull<<20))             // 64MB i8 [8192][8192]
#define FIXED_END (OFF_HQ + (64ull<<20))             // 129MB
// strip region (after FIXED_END): h fp16 [S][8192]

#define GLL(gp, lp) __builtin_amdgcn_global_load_lds( \
    (const __attribute__((address_space(1))) unsigned int*)(gp), \
    (__attribute__((address_space(3))) unsigned int*)(lp), 16, 0, 0)

// ---- |w| sums for all three weights (absmean scales), f64 totals ----
__global__ void k_wabs3(const float* __restrict__ w0, const float* __restrict__ w1,
                        const float* __restrict__ w2, double* __restrict__ dsum, int n4) {
  const float* w = blockIdx.y == 0 ? w0 : blockIdx.y == 1 ? w1 : w2;
  const f32x4* w4 = (const f32x4*)w;
  float s = 0.f;
  for (int i = blockIdx.x * blockDim.x + threadIdx.x; i < n4; i += gridDim.x * blockDim.x) {
    f32x4 v = w4[i];
    s += fabsf(v.x) + fabsf(v.y) + fabsf(v.z) + fabsf(v.w);
  }
  __shared__ float red[256];
  red[threadIdx.x] = s; __syncthreads();
  for (int o = 128; o > 0; o >>= 1) {
    if (threadIdx.x < o) red[threadIdx.x] += red[threadIdx.x + o];
    __syncthreads();
  }
  if (threadIdx.x == 0) atomicAdd(dsum + blockIdx.y, (double)red[0]);
}

// ---- ternary-quantize weights -> int8 {-1,0,1}.
// gate/up (y=0/1) write INTERLEAVED 16-row groups into wq_gu:
//   src row r -> R = 32*(r/16) + 16*y + (r%16); down (y=2) writes plain wq_d.
__global__ void k_quant_w3(const float* __restrict__ w0, const float* __restrict__ w1,
                           const float* __restrict__ w2, char* __restrict__ wq_gu,
                           char* __restrict__ wq_d, const double* __restrict__ dsum, int n4) {
  const int y = blockIdx.y;
  const float* w = y == 0 ? w0 : y == 1 ? w1 : w2;
  float scale = (float)(dsum[y] / (double)NW) + EPSQ;
  const f32x4* w4 = (const f32x4*)w;
  for (int i = blockIdx.x * blockDim.x + threadIdx.x; i < n4; i += gridDim.x * blockDim.x) {
    f32x4 v = w4[i];
    i8x4 o;
#pragma unroll
    for (int c = 0; c < 4; c++) {
      float q = rintf(v[c] / scale);
      q = fminf(1.f, fmaxf(-1.f, q));
      o[c] = (char)(int)q;
    }
    if (y < 2) {
      const int r = i >> 9, c4 = i & 511;        // 512 x f32x4 chunks per 2048-row
      const int R = ((r & ~15) << 1) + (y << 4) + (r & 15);
      *(i8x4*)&wq_gu[((size_t)R * 512 + c4) * 4] = o;
    } else {
      *(i8x4*)&wq_d[(size_t)i * 4] = o;
    }
  }
}

// ---- per-token int8 quantize x -> int8 + scale ----
__global__ void k_quant_x(const float* __restrict__ x, char* __restrict__ xq,
                          float* __restrict__ sx) {
  const int row = blockIdx.x;
  const int tid = threadIdx.x;
  const f32x4* xr = (const f32x4*)(x + (size_t)row * DM);
  f32x4 v0 = xr[tid * 2], v1 = xr[tid * 2 + 1];
  float m = 0.f;
#pragma unroll
  for (int c = 0; c < 4; c++) m = fmaxf(m, fmaxf(fabsf(v0[c]), fabsf(v1[c])));
  __shared__ float red[256];
  red[tid] = m; __syncthreads();
  for (int o = 128; o > 0; o >>= 1) {
    if (tid < o) red[tid] = fmaxf(red[tid], red[tid + o]);
    __syncthreads();
  }
  float sc = fmaxf(red[0], EPSQ) / 127.f;
  if (tid == 0) sx[row] = sc;
  i8x8 o;
#pragma unroll
  for (int c = 0; c < 4; c++) {
    float q0 = fminf(127.f, fmaxf(-128.f, rintf(v0[c] / sc)));
    float q1 = fminf(127.f, fmaxf(-128.f, rintf(v1[c] / sc)));
    o[c] = (char)(int)q0; o[c + 4] = (char)(int)q1;
  }
  *(i8x8*)&xq[(size_t)row * DM + tid * 8] = o;
}

// ---- row max + int8 quantize of h (fp16) ----
__global__ void k_hquant(const _Float16* __restrict__ h, char* __restrict__ hq,
                         float* __restrict__ sh) {
  const int row = blockIdx.x;
  const int tid = threadIdx.x;
  const f16x8* h8 = (const f16x8*)(h + (size_t)row * DF);
  float hv[32];
  float m = 0.f;
#pragma unroll
  for (int j = 0; j < 4; j++) {
    f16x8 v = h8[tid * 4 + j];
#pragma unroll
    for (int c = 0; c < 8; c++) {
      float f = (float)v[c];
      hv[j * 8 + c] = f;
      m = fmaxf(m, fabsf(f));
    }
  }
  __shared__ float red[256];
  red[tid] = m; __syncthreads();
  for (int o = 128; o > 0; o >>= 1) {
    if (tid < o) red[tid] = fmaxf(red[tid], red[tid + o]);
    __syncthreads();
  }
  float sc = fmaxf(red[0], EPSQ) / 127.f;
  if (tid == 0) sh[row] = sc;
#pragma unroll
  for (int jj = 0; jj < 4; jj++) {
    i8x8 o;
#pragma unroll
    for (int c = 0; c < 8; c++) {
      float q = fminf(127.f, fmaxf(-128.f, rintf(hv[jj * 8 + c] / sc)));
      o[c] = (char)(int)q;
    }
    *(i8x8*)&hq[(size_t)row * DF + tid * 32 + jj * 8] = o;
  }
}

// ---- 256x256-tile i8 MFMA GEMM (r10 K-loop: 4-deep BK=64 ring, frag
//      double-buffer, counted vmcnt 8/4/0, T2 swizzle via pre-swizzled GLL
//      source, setprio+sched_group interleave).
//      Block ordering: COLUMN-MAJOR lid->(m,n) so each XCD's contiguous lid
//      chunk keeps its B(weight)-panels L2-resident (fixes GEMM1's 7x
//      over-fetch: 273MB vs 40MB ideal). XCD swizzle bijective (nwg%8==0).
// FUSE=0: C[row*N+col] = acc * rowscale[row] * swA           (OT = float)
// FUSE=1: weight cols are gate/up interleaved (16-col groups); epilogue
//         computes h = sigmoid(g)*u per pair and writes fp16 h at
//         h[row*(N/2) + (n0+wn*64)/2 + p*16 + lr]            (OT = _Float16)
template<int FUSE, typename OT>
__global__ __launch_bounds__(512, 2)
void k_gemm8(const char* __restrict__ A, const char* __restrict__ B,
             OT* __restrict__ C, const float* __restrict__ rowscale,
             const double* __restrict__ dsumA, const double* __restrict__ dsumB,
             int N, int K) {
  __shared__ __align__(16) char sm[4][2][16384];

  const int tid = threadIdx.x;
  const int wv = tid >> 6;
  const int lane = tid & 63;
  const int wm = wv >> 2;
  const int wn = wv & 3;
  const int lr = lane & 15;
  const int g = lane >> 4;
  const int c3 = (lr >> 1) & 3;

  const int nwg = gridDim.x * gridDim.y;
  const int bid = blockIdx.y * gridDim.x + blockIdx.x;
  const int lid = (bid & 7) * (nwg >> 3) + (bid >> 3);
  const int gy = gridDim.y;           // number of 256-row m-blocks
  const int m0 = (lid % gy) << 8;     // column-major: m fastest
  const int n0 = (lid / gy) << 8;

  const float swA = (float)(*dsumA / (double)NW) + EPSQ;
  const float swB = (float)(*dsumB / (double)NW) + EPSQ;

  const int srow = lane >> 2;
  const int sslot = (lane & 3) ^ ((lane >> 3) & 3);
  const char* gA0 = A + (size_t)(m0 + wv * 32 + srow) * K + sslot * 16;
  const char* gA1 = gA0 + (size_t)16 * K;
  const char* gB0 = B + (size_t)(n0 + wv * 32 + srow) * K + sslot * 16;
  const char* gB1 = gB0 + (size_t)16 * K;
  const int dst0 = (wv * 32) * 64 + lane * 16;
  const int dst1 = dst0 + 1024;

#define STAGE(s) do { \
    const size_t ko_ = (size_t)(s) * 64; \
    char* pA_ = &sm[(s) & 3][0][0]; \
    char* pB_ = &sm[(s) & 3][1][0]; \
    GLL(gA0 + ko_, pA_ + dst0); \
    GLL(gA1 + ko_, pA_ + dst1); \
    GLL(gB0 + ko_, pB_ + dst0); \
    GLL(gB1 + ko_, pB_ + dst1); \
  } while (0)

  int32x4 acc[8][4];
  const int32x4 z4 = {0, 0, 0, 0};
#pragma unroll
  for (int m = 0; m < 8; m++)
#pragma unroll
    for (int n = 0; n < 4; n++) acc[m][n] = z4;

  const int NS = K >> 6;
  const int abase = (wm * 128 + lr) * 64 + ((g ^ c3) << 4);
  const int bbase = (wn * 64 + lr) * 64 + ((g ^ c3) << 4);

#define READS(NA, NB, slot_) do { \
    const char* smA_ = &sm[(slot_)][0][0]; \
    const char* smB_ = &sm[(slot_)][1][0]; \
    _Pragma("unroll") \
    for (int n = 0; n < 4; n++) NB[n] = *(const int32x4*)&smB_[bbase + n * 1024]; \
    _Pragma("unroll") \
    for (int m = 0; m < 8; m++) NA[m] = *(const int32x4*)&smA_[abase + m * 1024]; \
  } while (0)

#define MFMAS(CA, CB) do { \
    _Pragma("unroll") \
    for (int m = 0; m < 8; m++) \
      _Pragma("unroll") \
      for (int n = 0; n < 4; n++) \
        acc[m][n] = __builtin_amdgcn_mfma_i32_16x16x64_i8(CA[m], CB[n], acc[m][n], 0, 0, 0); \
  } while (0)

#define INTERLEAVE() do { \
    _Pragma("unroll") \
    for (int gg = 0; gg < 6; gg++) { \
      __builtin_amdgcn_sched_group_barrier(0x100, 2, 0); \
      __builtin_amdgcn_sched_group_barrier(0x008, 5, 0); \
    } \
    __builtin_amdgcn_sched_group_barrier(0x008, 2, 0); \
  } while (0)

#define ITER(sv, CA, CB, NA, NB) do { \
    const int s_ = (sv); \
    const int ahead_ = NS - 1 - s_; \
    if (ahead_ >= 3) { \
      STAGE(s_ + 3); \
      asm volatile("s_waitcnt vmcnt(8)" ::: "memory"); \
    } else if (ahead_ == 2) { \
      asm volatile("s_waitcnt vmcnt(4)" ::: "memory"); \
    } else { \
      asm volatile("s_waitcnt vmcnt(0)" ::: "memory"); \
    } \
    asm volatile("s_waitcnt lgkmcnt(0)" ::: "memory"); \
    __builtin_amdgcn_sched_barrier(0); \
    __builtin_amdgcn_s_barrier(); \
    __builtin_amdgcn_s_setprio(1); \
    READS(NA, NB, (s_ + 1) & 3); \
    MFMAS(CA, CB); \
    INTERLEAVE(); \
    __builtin_amdgcn_s_setprio(0); \
  } while (0)

  STAGE(0); STAGE(1); STAGE(2);
  asm volatile("s_waitcnt vmcnt(8)" ::: "memory");
  __builtin_amdgcn_s_barrier();

  int32x4 curA[8], curB[4], nxtA[8], nxtB[4];
  READS(curA, curB, 0);

  for (int s = 0; s + 1 < NS - 1; s += 2) {
    ITER(s, curA, curB, nxtA, nxtB);
    ITER(s + 1, nxtA, nxtB, curA, curB);
  }
  ITER(NS - 2, curA, curB, nxtA, nxtB);

  asm volatile("s_waitcnt lgkmcnt(0)" ::: "memory");
  __builtin_amdgcn_sched_barrier(0);
  __builtin_amdgcn_s_setprio(1);
  MFMAS(nxtA, nxtB);
  __builtin_amdgcn_s_setprio(0);
#undef ITER
#undef INTERLEAVE
#undef READS
#undef MFMAS
#undef STAGE

  // epilogue: C/D layout col = lane&15, row = (lane>>4)*4 + j
  if constexpr (FUSE) {
    const int hbase = (n0 + wn * 64) >> 1;
#pragma unroll
    for (int m = 0; m < 8; m++) {
#pragma unroll
      for (int j = 0; j < 4; j++) {
        const int row = m0 + wm * 128 + m * 16 + g * 4 + j;
        const float rs = rowscale[row];
#pragma unroll
        for (int p = 0; p < 2; p++) {
          const float gv = (float)acc[m][2 * p][j] * rs * swA;
          const float uv = (float)acc[m][2 * p + 1][j] * rs * swB;
          const float hv = uv / (1.f + expf(-gv));
          C[(size_t)row * (N >> 1) + hbase + p * 16 + lr] = (OT)hv;
        }
      }
    }
  } else {
#pragma unroll
    for (int m = 0; m < 8; m++) {
#pragma unroll
      for (int j = 0; j < 4; j++) {
        const int row = m0 + wm * 128 + m * 16 + g * 4 + j;
        const float rs = rowscale[row] * swA;
#pragma unroll
        for (int n = 0; n < 4; n++) {
          const int col = n0 + wn * 64 + n * 16 + lr;
          C[(size_t)row * N + col] = (OT)((float)acc[m][n][j] * rs);
        }
      }
    }
  }
}

extern "C" void kernel_launch(void* const* d_in, const int* in_sizes, int n_in,
                              void* d_out, int out_size, void* d_ws, size_t ws_size,
                              hipStream_t stream) {
  const float* x  = (const float*)d_in[0];
  const float* wg = (const float*)d_in[1];
  const float* wu = (const float*)d_in[2];
  const float* wd = (const float*)d_in[3];
  float* out = (float*)d_out;
  char* ws = (char*)d_ws;

  double* dsum = (double*)(ws + OFF_DSUM);
  float* sx = (float*)(ws + OFF_SX);
  float* sh = (float*)(ws + OFF_SH);
  char* xq   = ws + OFF_XQ;
  char* wcat = ws + OFF_WCAT;  // [16384][2048] gate/up interleaved (16-row groups)
  char* wdq  = ws + OFF_WDQ;
  char* hq   = ws + OFF_HQ;    // full [8192][8192] int8

  // strip sizing: per row need 8192*2 B (h fp16); S multiple of 256
  size_t avail = ws_size > FIXED_END ? ws_size - FIXED_END : 0;
  int S = 256;
  for (int cand = 8192; cand >= 256; cand >>= 1) {
    if ((size_t)cand * 16384ull <= avail) { S = cand; break; }
  }
  _Float16* hbuf = (_Float16*)(ws + FIXED_END);

  hipMemsetAsync(ws, 0, 64, stream);

  const int n4 = NW / 4;
  k_wabs3<<<dim3(2048, 3), 256, 0, stream>>>(wg, wu, wd, dsum, n4);
  k_quant_w3<<<dim3(2048, 3), 256, 0, stream>>>(wg, wu, wd, wcat, wdq, dsum, n4);
  k_quant_x<<<TOK, 256, 0, stream>>>(x, xq, sx);

  for (int base = 0; base < TOK; base += S) {
    // h = sigmoid(x@wg^T) * (x@wu^T) computed in one GEMM over interleaved
    // w_cat (N = 16384 weight cols -> 8192 fp16 h cols per row)
    k_gemm8<1, _Float16><<<dim3(NGU / 256, S / 256), 512, 0, stream>>>(
        xq + (size_t)base * DM, wcat, hbuf, sx + base,
        dsum + 0, dsum + 1, NGU, DM);

    k_hquant<<<S, 256, 0, stream>>>(hbuf, hq + (size_t)base * DF, sh + base);
  }

  // single down-projection GEMM over all rows (fp32 out)
  k_gemm8<0, float><<<dim3(DM / 256, TOK / 256), 512, 0, stream>>>(
      hq, wdq, out, sh, dsum + 2, dsum + 2, DM, DF);
}

// Round 17
// 616.447 us; speedup vs baseline: 1.2397x; 1.0089x over previous
//
#include <hip/hip_runtime.h>
#include <math.h>

#define EPSQ 1e-5f
#define TOK 8192
#define DM 2048
#define DF 8192
#define NW (DM*DF)
#define NGU 16384   // interleaved gate/up weight rows (16-row groups)

typedef float f32x4 __attribute__((ext_vector_type(4)));
typedef int   int32x4 __attribute__((ext_vector_type(4)));
typedef char  i8x4 __attribute__((ext_vector_type(4)));
typedef char  i8x8 __attribute__((ext_vector_type(8)));
typedef _Float16 f16x8 __attribute__((ext_vector_type(8)));

// ---- fixed workspace layout (bytes) ----
#define OFF_DSUM 0ull                                // 3 doubles
#define OFF_SX   (4ull<<10)                          // 8192 f32
#define OFF_SH   (40ull<<10)                         // 8192 f32
#define OFF_XQ   (1ull<<20)                          // 16MB i8 [8192][2048]
#define OFF_WCAT (OFF_XQ  + (16ull<<20))             // 32MB i8 [16384][2048] gate/up interleaved
#define OFF_WDQ  (OFF_WCAT + (32ull<<20))            // 16MB i8 [2048][8192]
#define OFF_HQ   (OFF_WDQ + (16ull<<20))             // 64MB i8 [8192][8192]
#define FIXED_END (OFF_HQ + (64ull<<20))             // 129MB
// strip region (after FIXED_END): h fp16 [S][8192]

#define GLL(gp, lp) __builtin_amdgcn_global_load_lds( \
    (const __attribute__((address_space(1))) unsigned int*)(gp), \
    (__attribute__((address_space(3))) unsigned int*)(lp), 16, 0, 0)

// ---- |w| sums for all three weights (absmean scales), f64 totals ----
__global__ void k_wabs3(const float* __restrict__ w0, const float* __restrict__ w1,
                        const float* __restrict__ w2, double* __restrict__ dsum, int n4) {
  const float* w = blockIdx.y == 0 ? w0 : blockIdx.y == 1 ? w1 : w2;
  const f32x4* w4 = (const f32x4*)w;
  float s = 0.f;
  for (int i = blockIdx.x * blockDim.x + threadIdx.x; i < n4; i += gridDim.x * blockDim.x) {
    f32x4 v = w4[i];
    s += fabsf(v.x) + fabsf(v.y) + fabsf(v.z) + fabsf(v.w);
  }
  __shared__ float red[256];
  red[threadIdx.x] = s; __syncthreads();
  for (int o = 128; o > 0; o >>= 1) {
    if (threadIdx.x < o) red[threadIdx.x] += red[threadIdx.x + o];
    __syncthreads();
  }
  if (threadIdx.x == 0) atomicAdd(dsum + blockIdx.y, (double)red[0]);
}

// ---- ternary-quantize weights -> int8 {-1,0,1}.
// gate/up (y=0/1) write INTERLEAVED 16-row groups into wq_gu:
//   src row r -> R = 32*(r/16) + 16*y + (r%16); down (y=2) writes plain wq_d.
__global__ void k_quant_w3(const float* __restrict__ w0, const float* __restrict__ w1,
                           const float* __restrict__ w2, char* __restrict__ wq_gu,
                           char* __restrict__ wq_d, const double* __restrict__ dsum, int n4) {
  const int y = blockIdx.y;
  const float* w = y == 0 ? w0 : y == 1 ? w1 : w2;
  float scale = (float)(dsum[y] / (double)NW) + EPSQ;
  const f32x4* w4 = (const f32x4*)w;
  for (int i = blockIdx.x * blockDim.x + threadIdx.x; i < n4; i += gridDim.x * blockDim.x) {
    f32x4 v = w4[i];
    i8x4 o;
#pragma unroll
    for (int c = 0; c < 4; c++) {
      float q = rintf(v[c] / scale);
      q = fminf(1.f, fmaxf(-1.f, q));
      o[c] = (char)(int)q;
    }
    if (y < 2) {
      const int r = i >> 9, c4 = i & 511;        // 512 x f32x4 chunks per 2048-row
      const int R = ((r & ~15) << 1) + (y << 4) + (r & 15);
      *(i8x4*)&wq_gu[((size_t)R * 512 + c4) * 4] = o;
    } else {
      *(i8x4*)&wq_d[(size_t)i * 4] = o;
    }
  }
}

// ---- per-token int8 quantize x -> int8 + scale ----
__global__ void k_quant_x(const float* __restrict__ x, char* __restrict__ xq,
                          float* __restrict__ sx) {
  const int row = blockIdx.x;
  const int tid = threadIdx.x;
  const f32x4* xr = (const f32x4*)(x + (size_t)row * DM);
  f32x4 v0 = xr[tid * 2], v1 = xr[tid * 2 + 1];
  float m = 0.f;
#pragma unroll
  for (int c = 0; c < 4; c++) m = fmaxf(m, fmaxf(fabsf(v0[c]), fabsf(v1[c])));
  __shared__ float red[256];
  red[tid] = m; __syncthreads();
  for (int o = 128; o > 0; o >>= 1) {
    if (tid < o) red[tid] = fmaxf(red[tid], red[tid + o]);
    __syncthreads();
  }
  float sc = fmaxf(red[0], EPSQ) / 127.f;
  if (tid == 0) sx[row] = sc;
  i8x8 o;
#pragma unroll
  for (int c = 0; c < 4; c++) {
    float q0 = fminf(127.f, fmaxf(-128.f, rintf(v0[c] / sc)));
    float q1 = fminf(127.f, fmaxf(-128.f, rintf(v1[c] / sc)));
    o[c] = (char)(int)q0; o[c + 4] = (char)(int)q1;
  }
  *(i8x8*)&xq[(size_t)row * DM + tid * 8] = o;
}

// ---- row max + int8 quantize of h (fp16) ----
__global__ void k_hquant(const _Float16* __restrict__ h, char* __restrict__ hq,
                         float* __restrict__ sh) {
  const int row = blockIdx.x;
  const int tid = threadIdx.x;
  const f16x8* h8 = (const f16x8*)(h + (size_t)row * DF);
  float hv[32];
  float m = 0.f;
#pragma unroll
  for (int j = 0; j < 4; j++) {
    f16x8 v = h8[tid * 4 + j];
#pragma unroll
    for (int c = 0; c < 8; c++) {
      float f = (float)v[c];
      hv[j * 8 + c] = f;
      m = fmaxf(m, fabsf(f));
    }
  }
  __shared__ float red[256];
  red[tid] = m; __syncthreads();
  for (int o = 128; o > 0; o >>= 1) {
    if (tid < o) red[tid] = fmaxf(red[tid], red[tid + o]);
    __syncthreads();
  }
  float sc = fmaxf(red[0], EPSQ) / 127.f;
  if (tid == 0) sh[row] = sc;
#pragma unroll
  for (int jj = 0; jj < 4; jj++) {
    i8x8 o;
#pragma unroll
    for (int c = 0; c < 8; c++) {
      float q = fminf(127.f, fmaxf(-128.f, rintf(hv[jj * 8 + c] / sc)));
      o[c] = (char)(int)q;
    }
    *(i8x8*)&hq[(size_t)row * DF + tid * 32 + jj * 8] = o;
  }
}

// ---- PERSISTENT 256x256-tile i8 MFMA GEMM (r16 K-loop: 4-deep BK=64 ring,
//      frag double-buffer, counted vmcnt 8/4/0, T2 swizzle via pre-swizzled
//      GLL source, setprio+sched_group interleave).
//      Grid = 256 blocks; each block loops over nv/256 tiles and issues the
//      NEXT tile's prologue stages BEFORE the current tile's epilogue, so
//      cold-start staging latency hides under epilogue VALU/stores.
//      Column-major lid->(m,n) + per-round XCD swizzle (r16 L2 behavior).
// FUSE=0: C[row*N+col] = acc * rowscale[row] * swA           (OT = float)
// FUSE=1: weight cols are gate/up interleaved (16-col groups); epilogue
//         computes h = sigmoid(g)*u per pair and writes fp16 h at
//         h[row*(N/2) + (n0+wn*64)/2 + p*16 + lr]            (OT = _Float16)
template<int FUSE, typename OT>
__global__ __launch_bounds__(512, 2)
void k_gemm8(const char* __restrict__ A, const char* __restrict__ B,
             OT* __restrict__ C, const float* __restrict__ rowscale,
             const double* __restrict__ dsumA, const double* __restrict__ dsumB,
             int M, int N, int K, int nv) {
  __shared__ __align__(16) char sm[4][2][16384];

  const int tid = threadIdx.x;
  const int wv = tid >> 6;
  const int lane = tid & 63;
  const int wm = wv >> 2;
  const int wn = wv & 3;
  const int lr = lane & 15;
  const int g = lane >> 4;
  const int c3 = (lr >> 1) & 3;

  const int b = blockIdx.x;
  const int lidr = (b & 7) * 32 + (b >> 3);   // XCD swizzle within a round of 256
  const int gy = M >> 8;
  const int T = nv >> 8;                      // tiles per block

  const float swA = (float)(*dsumA / (double)NW) + EPSQ;
  const float swB = (float)(*dsumB / (double)NW) + EPSQ;

  const int srow = lane >> 2;
  const int sslot = (lane & 3) ^ ((lane >> 3) & 3);
  const int dst0 = (wv * 32) * 64 + lane * 16;
  const int dst1 = dst0 + 1024;
  const int NS = K >> 6;
  const int abase = (wm * 128 + lr) * 64 + ((g ^ c3) << 4);
  const int bbase = (wn * 64 + lr) * 64 + ((g ^ c3) << 4);

  int m0 = 0, n0 = 0;
  const char *gA0 = nullptr, *gA1 = nullptr, *gB0 = nullptr, *gB1 = nullptr;

#define SETPTR(vt) do { \
    const int lid_ = (vt) * 256 + lidr; \
    m0 = (lid_ % gy) << 8; \
    n0 = (lid_ / gy) << 8; \
    gA0 = A + (size_t)(m0 + wv * 32 + srow) * K + sslot * 16; \
    gA1 = gA0 + (size_t)16 * K; \
    gB0 = B + (size_t)(n0 + wv * 32 + srow) * K + sslot * 16; \
    gB1 = gB0 + (size_t)16 * K; \
  } while (0)

#define STAGE(s) do { \
    const size_t ko_ = (size_t)(s) * 64; \
    char* pA_ = &sm[(s) & 3][0][0]; \
    char* pB_ = &sm[(s) & 3][1][0]; \
    GLL(gA0 + ko_, pA_ + dst0); \
    GLL(gA1 + ko_, pA_ + dst1); \
    GLL(gB0 + ko_, pB_ + dst0); \
    GLL(gB1 + ko_, pB_ + dst1); \
  } while (0)

#define READS(NA, NB, slot_) do { \
    const char* smA_ = &sm[(slot_)][0][0]; \
    const char* smB_ = &sm[(slot_)][1][0]; \
    _Pragma("unroll") \
    for (int n = 0; n < 4; n++) NB[n] = *(const int32x4*)&smB_[bbase + n * 1024]; \
    _Pragma("unroll") \
    for (int m = 0; m < 8; m++) NA[m] = *(const int32x4*)&smA_[abase + m * 1024]; \
  } while (0)

#define MFMAS(CA, CB) do { \
    _Pragma("unroll") \
    for (int m = 0; m < 8; m++) \
      _Pragma("unroll") \
      for (int n = 0; n < 4; n++) \
        acc[m][n] = __builtin_amdgcn_mfma_i32_16x16x64_i8(CA[m], CB[n], acc[m][n], 0, 0, 0); \
  } while (0)

#define INTERLEAVE() do { \
    _Pragma("unroll") \
    for (int gg = 0; gg < 6; gg++) { \
      __builtin_amdgcn_sched_group_barrier(0x100, 2, 0); \
      __builtin_amdgcn_sched_group_barrier(0x008, 5, 0); \
    } \
    __builtin_amdgcn_sched_group_barrier(0x008, 2, 0); \
  } while (0)

#define ITER(sv, CA, CB, NA, NB) do { \
    const int s_ = (sv); \
    const int ahead_ = NS - 1 - s_; \
    if (ahead_ >= 3) { \
      STAGE(s_ + 3); \
      asm volatile("s_waitcnt vmcnt(8)" ::: "memory"); \
    } else if (ahead_ == 2) { \
      asm volatile("s_waitcnt vmcnt(4)" ::: "memory"); \
    } else { \
      asm volatile("s_waitcnt vmcnt(0)" ::: "memory"); \
    } \
    asm volatile("s_waitcnt lgkmcnt(0)" ::: "memory"); \
    __builtin_amdgcn_sched_barrier(0); \
    __builtin_amdgcn_s_barrier(); \
    __builtin_amdgcn_s_setprio(1); \
    READS(NA, NB, (s_ + 1) & 3); \
    MFMAS(CA, CB); \
    INTERLEAVE(); \
    __builtin_amdgcn_s_setprio(0); \
  } while (0)

  int32x4 acc[8][4];
  const int32x4 z4 = {0, 0, 0, 0};
  int32x4 curA[8], curB[4], nxtA[8], nxtB[4];

  SETPTR(0);
  STAGE(0); STAGE(1); STAGE(2);

  for (int vt = 0; vt < T; ++vt) {
    const int em0 = m0, en0 = n0;   // epilogue coords for THIS tile

#pragma unroll
    for (int m = 0; m < 8; m++)
#pragma unroll
      for (int n = 0; n < 4; n++) acc[m][n] = z4;

    asm volatile("s_waitcnt vmcnt(8)" ::: "memory");
    __builtin_amdgcn_s_barrier();
    READS(curA, curB, 0);

    for (int s = 0; s + 1 < NS - 1; s += 2) {
      ITER(s, curA, curB, nxtA, nxtB);
      ITER(s + 1, nxtA, nxtB, curA, curB);
    }
    ITER(NS - 2, curA, curB, nxtA, nxtB);

    asm volatile("s_waitcnt lgkmcnt(0)" ::: "memory");
    __builtin_amdgcn_sched_barrier(0);
    __builtin_amdgcn_s_setprio(1);
    MFMAS(nxtA, nxtB);
    __builtin_amdgcn_s_setprio(0);

    // issue NEXT tile's prologue stages before the epilogue (latency hiding).
    // LDS hazard audit: slots 0,1,2 last read >=1 barrier ago (lgkm-drained);
    // slot 3 (still in flight for final MFMAS regs) is untouched.
    if (vt + 1 < T) {
      SETPTR(vt + 1);
      STAGE(0); STAGE(1); STAGE(2);
    }

    // epilogue: C/D layout col = lane&15, row = (lane>>4)*4 + j
    if constexpr (FUSE) {
      const int hbase = (en0 + wn * 64) >> 1;
#pragma unroll
      for (int m = 0; m < 8; m++) {
#pragma unroll
        for (int j = 0; j < 4; j++) {
          const int row = em0 + wm * 128 + m * 16 + g * 4 + j;
          const float rs = rowscale[row];
#pragma unroll
          for (int p = 0; p < 2; p++) {
            const float gv = (float)acc[m][2 * p][j] * rs * swA;
            const float uv = (float)acc[m][2 * p + 1][j] * rs * swB;
            const float hv = uv / (1.f + exp2f(gv * -1.44269504f));
            C[(size_t)row * (N >> 1) + hbase + p * 16 + lr] = (OT)hv;
          }
        }
      }
    } else {
#pragma unroll
      for (int m = 0; m < 8; m++) {
#pragma unroll
        for (int j = 0; j < 4; j++) {
          const int row = em0 + wm * 128 + m * 16 + g * 4 + j;
          const float rs = rowscale[row] * swA;
#pragma unroll
          for (int n = 0; n < 4; n++) {
            const int col = en0 + wn * 64 + n * 16 + lr;
            C[(size_t)row * N + col] = (OT)((float)acc[m][n][j] * rs);
          }
        }
      }
    }
  }
#undef ITER
#undef INTERLEAVE
#undef READS
#undef MFMAS
#undef STAGE
#undef SETPTR
}

extern "C" void kernel_launch(void* const* d_in, const int* in_sizes, int n_in,
                              void* d_out, int out_size, void* d_ws, size_t ws_size,
                              hipStream_t stream) {
  const float* x  = (const float*)d_in[0];
  const float* wg = (const float*)d_in[1];
  const float* wu = (const float*)d_in[2];
  const float* wd = (const float*)d_in[3];
  float* out = (float*)d_out;
  char* ws = (char*)d_ws;

  double* dsum = (double*)(ws + OFF_DSUM);
  float* sx = (float*)(ws + OFF_SX);
  float* sh = (float*)(ws + OFF_SH);
  char* xq   = ws + OFF_XQ;
  char* wcat = ws + OFF_WCAT;  // [16384][2048] gate/up interleaved (16-row groups)
  char* wdq  = ws + OFF_WDQ;
  char* hq   = ws + OFF_HQ;    // full [8192][8192] int8

  // strip sizing: per row need 8192*2 B (h fp16); S multiple of 256
  size_t avail = ws_size > FIXED_END ? ws_size - FIXED_END : 0;
  int S = 256;
  for (int cand = 8192; cand >= 256; cand >>= 1) {
    if ((size_t)cand * 16384ull <= avail) { S = cand; break; }
  }
  _Float16* hbuf = (_Float16*)(ws + FIXED_END);

  hipMemsetAsync(ws, 0, 64, stream);

  const int n4 = NW / 4;
  k_wabs3<<<dim3(2048, 3), 256, 0, stream>>>(wg, wu, wd, dsum, n4);
  k_quant_w3<<<dim3(2048, 3), 256, 0, stream>>>(wg, wu, wd, wcat, wdq, dsum, n4);
  k_quant_x<<<TOK, 256, 0, stream>>>(x, xq, sx);

  for (int base = 0; base < TOK; base += S) {
    // h = sigmoid(x@wg^T) * (x@wu^T) computed in one persistent GEMM over
    // interleaved w_cat (N = 16384 weight cols -> 8192 fp16 h cols per row)
    k_gemm8<1, _Float16><<<256, 512, 0, stream>>>(
        xq + (size_t)base * DM, wcat, hbuf, sx + base,
        dsum + 0, dsum + 1, S, NGU, DM, (S / 256) * (NGU / 256));

    k_hquant<<<S, 256, 0, stream>>>(hbuf, hq + (size_t)base * DF, sh + base);
  }

  // single persistent down-projection GEMM over all rows (fp32 out)
  k_gemm8<0, float><<<256, 512, 0, stream>>>(
      hq, wdq, out, sh, dsum + 2, dsum + 2, TOK, DM, DF,
      (TOK / 256) * (DM / 256));
}